// Round 1
// baseline (237.439 us; speedup 1.0000x reference)
//
#include <hip/hip_runtime.h>

#define RESERVOIR 8192
#define WINDOW 96
#define PRED 96
#define SEGMENTS 4096
#define TANH_K 2.8853900817779268f  /* 2/ln(2): tanh(z) = 1 - 2/(exp2(z*K)+1) */

// ---------------------------------------------------------------------------
// GEMM: Y[t][i] = TANH_K * dot(W_in[i,:], xseg[t,:])   (Y layout [t][i], t local to chunk)
// Block: 64 threads (1 wave), tile 64 i x 64 t, 8x8 micro-tile, K split in 3 phases of 32.
// LDS k-major [32][64] with XOR swizzle col ^= (k & 28): conflict-free reads/writes.
// ---------------------------------------------------------------------------
__global__ __launch_bounds__(64, 2) void gemm_kernel(const float* __restrict__ Win,
                                                     const float* __restrict__ xseg,
                                                     float* __restrict__ Y) {
    __shared__ float As[32 * 64];
    __shared__ float Bs[32 * 64];
    const int tid = threadIdx.x;
    const int i0 = blockIdx.y * 64;
    const int t0 = blockIdx.x * 64;
    const int ia = (tid & 7) * 8;   // i offset within tile (8 cols)
    const int tb = (tid >> 3) * 8;  // t offset within tile (8 rows)

    float acc[8][8];
#pragma unroll
    for (int r = 0; r < 8; ++r)
#pragma unroll
        for (int c = 0; c < 8; ++c) acc[r][c] = 0.f;

    for (int kk = 0; kk < WINDOW; kk += 32) {
        // Stage A and B half-tiles: 64 rows x 32 k = 512 float4 / 64 threads = 8 each
#pragma unroll
        for (int j = 0; j < 8; ++j) {
            const int f = tid + j * 64;
            const int i = f >> 3;        // row within tile [0,64)
            const int k4 = f & 7;        // float4 index within k-slab [0,8)
            const int kl = k4 * 4;       // local k [0,32)
            const int col = i ^ kl;      // kl & 28 == kl here (kl multiple of 4, <32)
            const float4 va = *(const float4*)(Win + (size_t)(i0 + i) * WINDOW + kk + kl);
            As[(kl + 0) * 64 + col] = va.x;
            As[(kl + 1) * 64 + col] = va.y;
            As[(kl + 2) * 64 + col] = va.z;
            As[(kl + 3) * 64 + col] = va.w;
            const float4 vb = *(const float4*)(xseg + (size_t)(t0 + i) * WINDOW + kk + kl);
            Bs[(kl + 0) * 64 + col] = vb.x;
            Bs[(kl + 1) * 64 + col] = vb.y;
            Bs[(kl + 2) * 64 + col] = vb.z;
            Bs[(kl + 3) * 64 + col] = vb.w;
        }
        __syncthreads();
#pragma unroll
        for (int kl = 0; kl < 32; ++kl) {
            const int fx = kl & 28;
            const float4 a0 = *(const float4*)&As[kl * 64 + ((ia) ^ fx)];
            const float4 a1 = *(const float4*)&As[kl * 64 + ((ia + 4) ^ fx)];
            const float4 b0 = *(const float4*)&Bs[kl * 64 + ((tb) ^ fx)];
            const float4 b1 = *(const float4*)&Bs[kl * 64 + ((tb + 4) ^ fx)];
            const float a[8] = {a0.x, a0.y, a0.z, a0.w, a1.x, a1.y, a1.z, a1.w};
            const float b[8] = {b0.x, b0.y, b0.z, b0.w, b1.x, b1.y, b1.z, b1.w};
#pragma unroll
            for (int r = 0; r < 8; ++r)
#pragma unroll
                for (int c = 0; c < 8; ++c) acc[r][c] = fmaf(a[r], b[c], acc[r][c]);
        }
        __syncthreads();
    }

    // Epilogue: Y[t][i], pre-scaled by TANH_K
#pragma unroll
    for (int c = 0; c < 8; ++c) {
        const size_t row = (size_t)(t0 + tb + c) * RESERVOIR + i0 + ia;
        float4 o0 = make_float4(acc[0][c] * TANH_K, acc[1][c] * TANH_K,
                                acc[2][c] * TANH_K, acc[3][c] * TANH_K);
        float4 o1 = make_float4(acc[4][c] * TANH_K, acc[5][c] * TANH_K,
                                acc[6][c] * TANH_K, acc[7][c] * TANH_K);
        *(float4*)(Y + row) = o0;
        *(float4*)(Y + row + 4) = o1;
    }
}

// ---------------------------------------------------------------------------
// Recurrence over one chunk: s = tanh_from_scaled(Y[t][i] + dK*s); Y pre-scaled by K.
// 8192 threads = 128 blocks x 64 (the algorithm has exactly 8192 chains).
// PF-deep register prefetch hides L3/HBM latency under the dependent VALU chain.
// ---------------------------------------------------------------------------
#define PF 16
__global__ __launch_bounds__(64) void rec_kernel(const float* __restrict__ Y,
                                                 const float* __restrict__ d,
                                                 float* __restrict__ s_ws, int T) {
    const int i = blockIdx.x * 64 + threadIdx.x;
    const float dk = d[i] * TANH_K;
    float s = s_ws[i];
    const float* p = Y + i;
    float buf[PF];
#pragma unroll
    for (int j = 0; j < PF; ++j) buf[j] = p[(size_t)j * RESERVOIR];
    for (int t0 = 0; t0 < T; t0 += PF) {
        float nxt[PF];
        const bool more = (t0 + PF) < T;
        if (more) {
#pragma unroll
            for (int j = 0; j < PF; ++j) nxt[j] = p[(size_t)(t0 + PF + j) * RESERVOIR];
        }
#pragma unroll
        for (int j = 0; j < PF; ++j) {
            const float zk = fmaf(dk, s, buf[j]);          // z * 2/ln2
            const float e = __builtin_amdgcn_exp2f(zk);    // e^{2z}
            const float r = __builtin_amdgcn_rcpf(e + 1.0f);
            s = fmaf(-2.0f, r, 1.0f);                      // tanh(z)
        }
        if (more) {
#pragma unroll
            for (int j = 0; j < PF; ++j) buf[j] = nxt[j];
        }
    }
    s_ws[i] = s;
}

// ---------------------------------------------------------------------------
// Output projection: out[p] = dot(W_out[p,:], s), p in [0,96)
// ---------------------------------------------------------------------------
__global__ __launch_bounds__(256) void out_kernel(const float* __restrict__ Wout,
                                                  const float* __restrict__ s,
                                                  float* __restrict__ out) {
    const int p = blockIdx.x;
    const int tid = threadIdx.x;
    float acc = 0.f;
#pragma unroll
    for (int j = 0; j < 8; ++j) {
        const int idx = (j * 256 + tid) * 4;
        const float4 w = *(const float4*)(Wout + (size_t)p * RESERVOIR + idx);
        const float4 sv = *(const float4*)(s + idx);
        acc = fmaf(w.x, sv.x, acc);
        acc = fmaf(w.y, sv.y, acc);
        acc = fmaf(w.z, sv.z, acc);
        acc = fmaf(w.w, sv.w, acc);
    }
#pragma unroll
    for (int off = 32; off > 0; off >>= 1) acc += __shfl_down(acc, off);
    __shared__ float red[4];
    if ((tid & 63) == 0) red[tid >> 6] = acc;
    __syncthreads();
    if (tid == 0) out[p] = red[0] + red[1] + red[2] + red[3];
}

__global__ void zero_kernel(float* __restrict__ s) {
    s[blockIdx.x * 256 + threadIdx.x] = 0.f;
}

extern "C" void kernel_launch(void* const* d_in, const int* in_sizes, int n_in,
                              void* d_out, int out_size, void* d_ws, size_t ws_size,
                              hipStream_t stream) {
    (void)in_sizes; (void)n_in; (void)out_size;
    const float* x    = (const float*)d_in[0];
    const float* Win  = (const float*)d_in[1];
    const float* dvec = (const float*)d_in[2];
    const float* Wout = (const float*)d_in[3];
    float* out = (float*)d_out;

    // Chunk of segments: Y chunk (Tc*8192 f32) + state (8192 f32) must fit ws.
    int Tc = 1024;
    while (Tc > 64 && ((size_t)Tc * RESERVOIR * 4 + (size_t)RESERVOIR * 4) > ws_size) Tc >>= 1;

    float* Y = (float*)d_ws;
    float* s_ws = (float*)((char*)d_ws + (size_t)Tc * RESERVOIR * 4);

    zero_kernel<<<dim3(RESERVOIR / 256), 256, 0, stream>>>(s_ws);
    for (int t0 = 0; t0 < SEGMENTS; t0 += Tc) {
        gemm_kernel<<<dim3(Tc / 64, RESERVOIR / 64), 64, 0, stream>>>(
            Win, x + (size_t)t0 * WINDOW, Y);
        rec_kernel<<<dim3(RESERVOIR / 64), 64, 0, stream>>>(Y, dvec, s_ws, Tc);
    }
    out_kernel<<<dim3(PRED), 256, 0, stream>>>(Wout, s_ws, out);
}

// Round 2
// 157.004 us; speedup vs baseline: 1.5123x; 1.5123x over previous
//
#include <hip/hip_runtime.h>

#define RESERVOIR 8192
#define WINDOW 96
#define PRED 96
#define SEGMENTS 4096
#define TC 1024                     /* segments per chunk */
#define NCHUNK (SEGMENTS / TC)      /* 4 */
#define TANH_K 2.8853900817779268f  /* 2/ln2 : tanh(z) = 1 - 2/(exp2(z*K)+1) */
#define PF 32                       /* rec prefetch slab (steps) */

typedef unsigned short u16;
typedef unsigned int u32;
typedef __attribute__((ext_vector_type(8))) short bf16x8;
typedef __attribute__((ext_vector_type(4))) float floatx4;

__device__ __forceinline__ u16 f2bf(float f) {
    u32 u = __float_as_uint(f);
    return (u16)((u + 0x7fffu + ((u >> 16) & 1u)) >> 16);
}
__device__ __forceinline__ float bf2f(u16 h) {
    return __uint_as_float((u32)h << 16);
}

// ---------------------------------------------------------------------------
// prep: pack Win and x into fragment-ordered bf16 hi/lo arrays + zero state.
// Fragment layout (per 16-row x 32-k tile): lane l -> row = l&15, 8 elems at
// k = kt*32 + 4*(l>>4) + {0..3} and +16. (Any bijection works if A and B use
// the same one.) Pack index: [(tile_row*3 + kt)*64 + lane]*8 + j.
// ---------------------------------------------------------------------------
__global__ __launch_bounds__(256) void prep_kernel(const float* __restrict__ x,
                                                   const float* __restrict__ Win,
                                                   u16* __restrict__ Wph, u16* __restrict__ Wpl,
                                                   u16* __restrict__ Xph, u16* __restrict__ Xpl,
                                                   float* __restrict__ s_ws) {
    const int gid = blockIdx.x * 256 + threadIdx.x;
    const float* src;
    u16 *dh, *dl;
    int idx;
    if (blockIdx.x < 384) {            // Win: 512 row-tiles x 3 kt x 64 lanes
        idx = gid;
        const int tile = idx >> 6, lane = idx & 63;
        const int rt = tile / 3, kt = tile % 3;
        src = Win + (size_t)(rt * 16 + (lane & 15)) * WINDOW + kt * 32 + 4 * (lane >> 4);
        dh = Wph; dl = Wpl;
    } else if (blockIdx.x < 576) {     // x: 256 seg-tiles x 3 kt x 64 lanes
        idx = gid - 384 * 256;
        const int tile = idx >> 6, lane = idx & 63;
        const int rt = tile / 3, kt = tile % 3;
        src = x + (size_t)(rt * 16 + (lane & 15)) * WINDOW + kt * 32 + 4 * (lane >> 4);
        dh = Xph; dl = Xpl;
    } else {                           // zero state
        s_ws[gid - 576 * 256] = 0.f;
        return;
    }
    const float4 v0 = *(const float4*)(src);
    const float4 v1 = *(const float4*)(src + 16);
    const float f[8] = {v0.x, v0.y, v0.z, v0.w, v1.x, v1.y, v1.z, v1.w};
    u16 h[8], l[8];
#pragma unroll
    for (int j = 0; j < 8; ++j) {
        h[j] = f2bf(f[j]);
        l[j] = f2bf(f[j] - bf2f(h[j]));
    }
    *(uint4*)(dh + (size_t)idx * 8) = make_uint4(h[0] | (u32)h[1] << 16, h[2] | (u32)h[3] << 16,
                                                 h[4] | (u32)h[5] << 16, h[6] | (u32)h[7] << 16);
    *(uint4*)(dl + (size_t)idx * 8) = make_uint4(l[0] | (u32)l[1] << 16, l[2] | (u32)l[3] << 16,
                                                 l[4] | (u32)l[5] << 16, l[6] | (u32)l[7] << 16);
}

// ---------------------------------------------------------------------------
// rec: 8192 chains, 4-op dependent step. z carries; y' = yK + dk off-chain.
// ---------------------------------------------------------------------------
__device__ __forceinline__ void load_slab(u16 (&r)[PF], const u16* p, int slab) {
#pragma unroll
    for (int j = 0; j < PF; ++j) r[j] = p[(size_t)(slab * PF + j) * RESERVOIR];
}

__device__ __forceinline__ void rec_path(const u16* __restrict__ Yin,
                                         const float* __restrict__ dvec,
                                         float* __restrict__ s_ws) {
    const int tid = blockIdx.x * 256 + threadIdx.x;
    const float dk = dvec[tid] * TANH_K;
    const float n2dk = -2.0f * dk;
    const float s0 = s_ws[tid];
    const u16* p = Yin + tid;
    u16 rA[PF], rB[PF];
    float y[PF];
    float z;
#define CVTS(src) _Pragma("unroll") for (int j = 0; j < PF; ++j) y[j] = bf2f(src[j]) + dk;
#define STEPN(yv) { float e = __builtin_amdgcn_exp2f(z); float r = __builtin_amdgcn_rcpf(e + 1.0f); z = fmaf(n2dk, r, (yv)); }
    load_slab(rA, p, 0);
    load_slab(rB, p, 1);
    CVTS(rA)
    load_slab(rA, p, 2);
    z = fmaf(dk, s0 - 1.0f, y[0]);
#pragma unroll
    for (int j = 1; j < PF; ++j) STEPN(y[j])
    for (int sl = 1; sl <= 29; sl += 2) {
        CVTS(rB)
        load_slab(rB, p, sl + 2);
#pragma unroll
        for (int j = 0; j < PF; ++j) STEPN(y[j])
        CVTS(rA)
        if (sl + 3 <= 31) load_slab(rA, p, sl + 3);
#pragma unroll
        for (int j = 0; j < PF; ++j) STEPN(y[j])
    }
    CVTS(rB)
#pragma unroll
    for (int j = 0; j < PF; ++j) STEPN(y[j])
    const float e = __builtin_amdgcn_exp2f(z);
    const float r = __builtin_amdgcn_rcpf(e + 1.0f);
    s_ws[tid] = fmaf(-2.0f, r, 1.0f);
#undef CVTS
#undef STEPN
}

// ---------------------------------------------------------------------------
// gemm: bf16x3 split MFMA. Block = 4 waves (2x2), wave = 64t x 64i (4x4 frags).
// Y[t_local][i] bf16, pre-scaled by TANH_K.
// ---------------------------------------------------------------------------
__device__ __forceinline__ void gemm_path(int bid, int chunk,
                                          const u16* __restrict__ Xph, const u16* __restrict__ Xpl,
                                          const u16* __restrict__ Wph, const u16* __restrict__ Wpl,
                                          u16* __restrict__ Yout) {
    const int lane = threadIdx.x & 63;
    const int wave = threadIdx.x >> 6;
    const int wt = wave >> 1, wi = wave & 1;
    const int tb = bid >> 6, ib = bid & 63;           // 8 t-blocks x 64 i-blocks
    const int tt0 = chunk * (TC / 16) + tb * 8 + wt * 4;  // global t-frag-tile base
    const int it0 = ib * 8 + wi * 4;

    floatx4 acc[4][4];
#pragma unroll
    for (int m = 0; m < 4; ++m)
#pragma unroll
        for (int n = 0; n < 4; ++n) acc[m][n] = (floatx4)0.f;

#pragma unroll
    for (int kt = 0; kt < 3; ++kt) {
        bf16x8 ah[4], al[4], bh[4], bl[4];
#pragma unroll
        for (int m = 0; m < 4; ++m) {
            const size_t ax = ((size_t)((tt0 + m) * 3 + kt) * 64 + lane) * 8;
            ah[m] = *(const bf16x8*)(Xph + ax);
            al[m] = *(const bf16x8*)(Xpl + ax);
            const size_t bx = ((size_t)((it0 + m) * 3 + kt) * 64 + lane) * 8;
            bh[m] = *(const bf16x8*)(Wph + bx);
            bl[m] = *(const bf16x8*)(Wpl + bx);
        }
#pragma unroll
        for (int m = 0; m < 4; ++m)
#pragma unroll
            for (int n = 0; n < 4; ++n) {
                acc[m][n] = __builtin_amdgcn_mfma_f32_16x16x32_bf16(ah[m], bh[n], acc[m][n], 0, 0, 0);
                acc[m][n] = __builtin_amdgcn_mfma_f32_16x16x32_bf16(ah[m], bl[n], acc[m][n], 0, 0, 0);
                acc[m][n] = __builtin_amdgcn_mfma_f32_16x16x32_bf16(al[m], bh[n], acc[m][n], 0, 0, 0);
            }
    }

    const int g = lane >> 4, c = lane & 15;
#pragma unroll
    for (int m = 0; m < 4; ++m) {
        const int trow0 = (tb * 8 + wt * 4 + m) * 16 + 4 * g;   // chunk-local t
#pragma unroll
        for (int n = 0; n < 4; ++n) {
            const int col = (it0 + n) * 16 + c;
#pragma unroll
            for (int r = 0; r < 4; ++r)
                Yout[(size_t)(trow0 + r) * RESERVOIR + col] = f2bf(acc[m][n][r] * TANH_K);
        }
    }
}

__global__ __launch_bounds__(256) void main_kernel(const u16* __restrict__ Xph, const u16* __restrict__ Xpl,
                                                   const u16* __restrict__ Wph, const u16* __restrict__ Wpl,
                                                   u16* __restrict__ Yout, const u16* __restrict__ Yin,
                                                   const float* __restrict__ dvec, float* __restrict__ s_ws,
                                                   int chunk, int n_rec) {
    if ((int)blockIdx.x < n_rec) {
        rec_path(Yin, dvec, s_ws);
        return;
    }
    gemm_path(blockIdx.x - n_rec, chunk, Xph, Xpl, Wph, Wpl, Yout);
}

// ---------------------------------------------------------------------------
// out projection: out[p] = dot(W_out[p,:], s)
// ---------------------------------------------------------------------------
__global__ __launch_bounds__(256) void out_kernel(const float* __restrict__ Wout,
                                                  const float* __restrict__ s,
                                                  float* __restrict__ out) {
    const int p = blockIdx.x;
    const int tid = threadIdx.x;
    float acc = 0.f;
#pragma unroll
    for (int j = 0; j < 8; ++j) {
        const int idx = (j * 256 + tid) * 4;
        const float4 w = *(const float4*)(Wout + (size_t)p * RESERVOIR + idx);
        const float4 sv = *(const float4*)(s + idx);
        acc = fmaf(w.x, sv.x, acc);
        acc = fmaf(w.y, sv.y, acc);
        acc = fmaf(w.z, sv.z, acc);
        acc = fmaf(w.w, sv.w, acc);
    }
#pragma unroll
    for (int off = 32; off > 0; off >>= 1) acc += __shfl_down(acc, off);
    __shared__ float red[4];
    if ((tid & 63) == 0) red[tid >> 6] = acc;
    __syncthreads();
    if (tid == 0) out[p] = red[0] + red[1] + red[2] + red[3];
}

extern "C" void kernel_launch(void* const* d_in, const int* in_sizes, int n_in,
                              void* d_out, int out_size, void* d_ws, size_t ws_size,
                              hipStream_t stream) {
    (void)in_sizes; (void)n_in; (void)out_size; (void)ws_size;
    const float* x    = (const float*)d_in[0];
    const float* Win  = (const float*)d_in[1];
    const float* dvec = (const float*)d_in[2];
    const float* Wout = (const float*)d_in[3];
    float* out = (float*)d_out;

    // ws layout (needs ~38.4 MB; ws is 256 MiB)
    char* w = (char*)d_ws;
    const size_t ybytes = (size_t)TC * RESERVOIR * 2;          // 16 MiB each
    u16* Y0 = (u16*)w;
    u16* Y1 = (u16*)(w + ybytes);
    float* s_ws = (float*)(w + 2 * ybytes);
    u16* Xph = (u16*)(w + 2 * ybytes + RESERVOIR * 4);
    u16* Xpl = Xph + (size_t)SEGMENTS * WINDOW;                // 393216 each
    u16* Wph = Xpl + (size_t)SEGMENTS * WINDOW;
    u16* Wpl = Wph + (size_t)RESERVOIR * WINDOW;               // 786432 each

    prep_kernel<<<608, 256, 0, stream>>>(x, Win, Wph, Wpl, Xph, Xpl, s_ws);
    // chunk 0 gemm only
    main_kernel<<<512, 256, 0, stream>>>(Xph, Xpl, Wph, Wpl, Y0, nullptr, dvec, s_ws, 0, 0);
    // gemm c+1 overlapped with rec c
    main_kernel<<<544, 256, 0, stream>>>(Xph, Xpl, Wph, Wpl, Y1, Y0, dvec, s_ws, 1, 32);
    main_kernel<<<544, 256, 0, stream>>>(Xph, Xpl, Wph, Wpl, Y0, Y1, dvec, s_ws, 2, 32);
    main_kernel<<<544, 256, 0, stream>>>(Xph, Xpl, Wph, Wpl, Y1, Y0, dvec, s_ws, 3, 32);
    // final rec only
    main_kernel<<<32, 256, 0, stream>>>(Xph, Xpl, Wph, Wpl, nullptr, Y1, dvec, s_ws, -1, 32);
    out_kernel<<<PRED, 256, 0, stream>>>(Wout, s_ws, out);
}